// Round 2
// baseline (702.186 us; speedup 1.0000x reference)
//
#include <hip/hip_runtime.h>
#include <stdint.h>

// ---------------------------------------------------------------------------
// SpatialConvModule: 4-direction spatial propagation (SCNN-like) + fusion GEMM
// Plan:
//   K0 prep:      bf16 weight repack (per-direction middle row/col taps),
//                 BN/bias fold -> (scale,shift), fusion weight bf16 repack
//   K1 transpose: x NCHW fp32 -> xT NHWC fp32 (serves all 4 scan directions)
//   K2 scan:      160 WGs = (4 dir x 8 batch) x 5 chunks of 32 inner columns.
//                 Each WG runs the full 160-step recurrence; per step one
//                 (M=32,N=128,K=384) bf16 MFMA GEMM; chunk-boundary y values
//                 exchanged via tagged 32-bit agent-scope atomics (fence-free).
//                 R2: in-loop barriers are lgkmcnt-only (raw s_barrier) so
//                 global loads/stores are never drained at a barrier.
//   K3 fusion:    (M=204800,N=128,K=512) bf16 GEMM + BN + ReLU -> NCHW fp32
// ---------------------------------------------------------------------------

typedef __attribute__((ext_vector_type(8))) __bf16 bf16x8;
typedef __attribute__((ext_vector_type(4))) float f32x4;

#define DEV static __device__ __forceinline__

DEV unsigned short f2bf(float f) {
  union { float f; unsigned int u; } v; v.f = f;
  unsigned int u = v.u;
  u += 0x7fffu + ((u >> 16) & 1u);   // round-to-nearest-even
  return (unsigned short)(u >> 16);
}
DEV float bf2f(unsigned short s) {
  union { float f; unsigned int u; } v; v.u = ((unsigned int)s) << 16;
  return v.f;
}
DEV f32x4 mfma16(bf16x8 a, bf16x8 b, f32x4 c) {
  return __builtin_amdgcn_mfma_f32_16x16x32_bf16(a, b, c, 0, 0, 0);
}
// LDS-only barrier: does NOT drain vmcnt (global loads/stores stay in flight).
// __syncthreads() would emit s_waitcnt vmcnt(0) and stall ~300-900 cyc/step on
// store acks + prefetch drains. All cross-thread hazards at these points are
// LDS-only, so lgkmcnt(0) + s_barrier is sufficient.
DEV void barrier_lds() {
  asm volatile("s_waitcnt lgkmcnt(0)\n\ts_barrier" ::: "memory");
}

constexpr int Hc = 160, Wc = 160, Bn = 8, Cc = 128;
constexpr int CHUNK = 32, NCH = 5;   // 5 chunks of 32 along the inner axis
constexpr int SPAD = 136;            // sT row stride in bf16 (136*2B: 2-way bank alias = free)

// workspace layout (bytes)
constexpr long WS_XT    = 0;                         // fp32 [8][160][160][128] = 104857600
constexpr long WS_WPREP = 104857600;                 // bf16 [4][128][384]      = 393216
constexpr long WS_EPI   = 105250816;                 // float2 [512]            = 4096
constexpr long WS_FWT   = 105254912;                 // bf16 [128][512]         = 131072
constexpr long WS_FEPI  = 105385984;                 // float2 [128]            = 1024
constexpr long WS_FEAT  = 105387008;                 // bf16 [8][160][160][512] = 209715200
constexpr long WS_EX    = 315102208;                 // u32 [160][2][2][128]    = 327680
constexpr long WS_TOTAL = 315429888;

// ---------------------------------------------------------------------------
__global__ void prep_kernel(const float* __restrict__ kern, const float* __restrict__ bias,
                            const float* __restrict__ bg, const float* __restrict__ bb,
                            const float* __restrict__ bm, const float* __restrict__ bv,
                            const float* __restrict__ fw, const float* __restrict__ fb2,
                            const float* __restrict__ fg, const float* __restrict__ fbt,
                            const float* __restrict__ fm, const float* __restrict__ fv,
                            unsigned short* __restrict__ wprep, float2* __restrict__ epi,
                            unsigned short* __restrict__ fwT, float2* __restrict__ fepi)
{
  int idx = blockIdx.x * 256 + threadIdx.x;
  if (idx < 196608) {                 // wprep[d][o][t*128+c] = kmid[d][o][c][t]
    int c = idx & 127;
    int t = (idx >> 7) % 3;
    int o = (idx / 384) & 127;
    int d = idx / 49152;
    int kh = (d < 2) ? 1 : t;         // rows use k[:,:,1,:], cols use k[:,:,:,1]
    int kw = (d < 2) ? t : 1;
    wprep[idx] = f2bf(kern[(((d * 128 + o) * 128 + c) * 3 + kh) * 3 + kw]);
  }
  int i2 = idx - 196608;              // fusion weights [o][d*128+c] -> bf16
  if (i2 >= 0 && i2 < 65536) fwT[i2] = f2bf(fw[i2]);
  int i3 = idx - 262144;              // per-(d,o) BN fold: y = conv*scale + shift (pre-activation)
  if (i3 >= 0 && i3 < 512) {
    float sc = bg[i3] / sqrtf(bv[i3] + 1e-5f);
    epi[i3] = make_float2(sc, (bias[i3] - bm[i3]) * sc + bb[i3]);
  }
  int i4 = idx - 262656;              // fusion BN fold
  if (i4 >= 0 && i4 < 128) {
    float sc = fg[i4] / sqrtf(fv[i4] + 1e-5f);
    fepi[i4] = make_float2(sc, (fb2[i4] - fm[i4]) * sc + fbt[i4]);
  }
}

// ---------------------------------------------------------------------------
__global__ void transpose_kernel(const float* __restrict__ x, float* __restrict__ xT)
{
  __shared__ float tile[32][33];
  int b = blockIdx.z, h = blockIdx.y;
  int c0 = (blockIdx.x / 5) * 32, w0 = (blockIdx.x % 5) * 32;
  int tx = threadIdx.x & 31, ty = threadIdx.x >> 5;
#pragma unroll
  for (int r = 0; r < 4; r++) {
    int c = c0 + ty + 8 * r;
    tile[ty + 8 * r][tx] = x[(((long)b * 128 + c) * 160 + h) * 160 + w0 + tx];
  }
  __syncthreads();
#pragma unroll
  for (int r = 0; r < 4; r++) {
    int w = w0 + ty + 8 * r;
    xT[(((long)b * 160 + h) * 160 + w) * 128 + c0 + tx] = tile[tx][ty + 8 * r];
  }
}

// ---------------------------------------------------------------------------
// scan: bid = q*32 + (d*8+b); bid%8 invariant over q => group stays on one XCD
__global__ __launch_bounds__(256, 1) void scan_kernel(
    const float* __restrict__ xT, const unsigned short* __restrict__ wprep,
    const float2* __restrict__ epi, const float* __restrict__ prelu_a,
    unsigned short* __restrict__ featbuf, unsigned int* __restrict__ ex)
{
  __shared__ unsigned short sT[34 * SPAD];  // rows: u-1 .. u+32 (halo top/bottom)

  const int bid = blockIdx.x;
  const int q = bid >> 5;          // chunk 0..4
  const int g = bid & 31;          // d*8 + b
  const int d = g >> 3, b = g & 7;
  const bool row_mode = (d < 2);
  const bool rev = (d & 1);
  const int u0 = q * CHUNK;
  const int tid = threadIdx.x;
  const int lane = tid & 63;
  const int wv = tid >> 6;         // wave 0..3; wave handles n-tiles {2wv, 2wv+1}
  const int ncol = lane & 15;      // A-row / B-col / D-col lane index
  const int kq = lane >> 4;        // k-quad / D-row-quad

  const long si = row_mode ? (long)Wc * Cc : (long)Cc;   // scan-axis stride in xT
  const long su = row_mode ? (long)Cc : (long)Wc * Cc;   // inner-axis stride in xT
  const long fi = row_mode ? (long)Wc * 512 : (long)512; // scan-axis stride in feat
  const long fu = row_mode ? (long)512 : (long)Wc * 512; // inner-axis stride in feat
  const float* xb = xT + (long)b * Hc * Wc * Cc;
  unsigned short* fbp = featbuf + (long)b * Hc * Wc * 512 + d * 128;

  // B fragments: stay in registers for all 160 steps. B[k=t*128+c][n=o].
  bf16x8 Bfrag[2][12];
  float2 ep[2];
#pragma unroll
  for (int j = 0; j < 2; j++) {
    const int o = (wv * 2 + j) * 16 + ncol;
    const unsigned short* wp = wprep + ((long)(d * 128 + o)) * 384;
#pragma unroll
    for (int kt = 0; kt < 12; kt++)
      Bfrag[j][kt] = *(const bf16x8*)(wp + kt * 32 + kq * 8);
    ep[j] = epi[d * 128 + o];
  }
  const float aslope = prelu_a[d];

  unsigned int* ex_self = ex + (long)bid * 512;
  const unsigned int* ex_leftp  = ex + (long)(bid - 32) * 512 + 256; // left nbr, its u=31 side
  const unsigned int* ex_rightp = ex + (long)(bid + 32) * 512;       // right nbr, its u=0 side

  // prologue: s(t=0) = x(i0) + 0
  const int i0 = rev ? (Hc - 1) : 0;
  for (int e = tid; e < 34 * 64; e += 256) {
    const int u = e >> 6, cp = e & 63;
    const int uu = u0 + u - 1;
    unsigned int sv = 0;
    if (uu >= 0 && uu < 160) {
      const float2 xv2 = *(const float2*)(xb + (long)i0 * si + (long)uu * su + cp * 2);
      sv = (unsigned int)f2bf(xv2.x) | ((unsigned int)f2bf(xv2.y) << 16);
    }
    *(unsigned int*)&sT[u * SPAD + cp * 2] = sv;
  }
  barrier_lds();

#pragma unroll 1
  for (int t = 0; t < 160; t++) {
    const int i = rev ? (159 - t) : t;
    const int inext = rev ? (i - 1) : (i + 1);
    const bool last = (t == 159);
    const int par = t & 1;

    // prefetch next scan-line x into registers (hidden under MFMA phase)
    float2 xv[8];
    float xh = 0.f;
    if (!last) {
#pragma unroll
      for (int rr = 0; rr < 8; rr++) {
        const int e = tid + rr * 256;
        const int u = e >> 6, cp = e & 63;
        xv[rr] = *(const float2*)(xb + (long)inext * si + (long)(u0 + u) * su + cp * 2);
      }
      const int o = tid & 127;
      const int ug = (tid < 128) ? (u0 - 1) : (u0 + CHUNK);
      if (ug >= 0 && ug < 160) xh = xb[(long)inext * si + (long)ug * su + o];
    }

    // MFMA: D[m=u][n=o] = sum_k s[m+t-1][c] * w[o][t*128+c]
    f32x4 acc[2][2];
#pragma unroll
    for (int mt = 0; mt < 2; mt++)
#pragma unroll
      for (int j = 0; j < 2; j++)
        acc[mt][j] = (f32x4){0.f, 0.f, 0.f, 0.f};
#pragma unroll
    for (int kt = 0; kt < 12; kt++) {
      const int tt = kt >> 2;                         // tap 0..2
      const int c0 = ((kt & 3) << 5) + (kq << 3);     // c within tap
      const bf16x8 A0 = *(const bf16x8*)&sT[(ncol + tt) * SPAD + c0];
      const bf16x8 A1 = *(const bf16x8*)&sT[(16 + ncol + tt) * SPAD + c0];
      acc[0][0] = mfma16(A0, Bfrag[0][kt], acc[0][0]);
      acc[0][1] = mfma16(A0, Bfrag[1][kt], acc[0][1]);
      acc[1][0] = mfma16(A1, Bfrag[0][kt], acc[1][0]);
      acc[1][1] = mfma16(A1, Bfrag[1][kt], acc[1][1]);
    }

    // epilogue: BN fold + PReLU, to bf16
    unsigned short yb[2][2][4];
#pragma unroll
    for (int mt = 0; mt < 2; mt++)
#pragma unroll
      for (int j = 0; j < 2; j++)
#pragma unroll
        for (int r = 0; r < 4; r++) {
          float v = acc[mt][j][r] * ep[j].x + ep[j].y;
          v = (v >= 0.f) ? v : (aslope * v);
          yb[mt][j][r] = f2bf(v);
        }

    // publish boundary columns ASAP: one word = (t+1)<<16 | bf16(y)
    {
      const unsigned int tagv = ((unsigned int)(t + 1)) << 16;
      if (kq == 0) {                          // D row 0 -> u_local = 0
#pragma unroll
        for (int j = 0; j < 2; j++) {
          const int o = (wv * 2 + j) * 16 + ncol;
          __hip_atomic_store(&ex_self[par * 128 + o], tagv | (unsigned int)yb[0][j][0],
                             __ATOMIC_RELAXED, __HIP_MEMORY_SCOPE_AGENT);
        }
      }
      if (kq == 3) {                          // D row 15 of m-tile 1 -> u_local = 31
#pragma unroll
        for (int j = 0; j < 2; j++) {
          const int o = (wv * 2 + j) * 16 + ncol;
          __hip_atomic_store(&ex_self[256 + par * 128 + o], tagv | (unsigned int)yb[1][j][3],
                             __ATOMIC_RELAXED, __HIP_MEMORY_SCOPE_AGENT);
        }
      }
    }

    barrier_lds();   // everyone done reading sT (LDS-only; vmem stays in flight)

    // y -> sT rows 1..32 (becomes next step's recurrence input)
#pragma unroll
    for (int mt = 0; mt < 2; mt++)
#pragma unroll
      for (int j = 0; j < 2; j++)
#pragma unroll
        for (int r = 0; r < 4; r++)
          sT[(1 + mt * 16 + kq * 4 + r) * SPAD + (wv * 2 + j) * 16 + ncol] = yb[mt][j][r];

    barrier_lds();   // y visible to all threads

    // coalesced feat store + in-place next-s build (s = x_next + y)
#pragma unroll
    for (int rr = 0; rr < 8; rr++) {
      const int e = tid + rr * 256;
      const int u = e >> 6, cp = e & 63;
      const unsigned int yw = *(const unsigned int*)&sT[(1 + u) * SPAD + cp * 2];
      unsigned short* fr = fbp + (long)i * fi + (long)(u0 + u) * fu;
      ((unsigned int*)fr)[cp] = yw;
      if (!last) {
        const float y0 = bf2f((unsigned short)(yw & 0xffff));
        const float y1 = bf2f((unsigned short)(yw >> 16));
        const unsigned int sv = (unsigned int)f2bf(xv[rr].x + y0)
                              | ((unsigned int)f2bf(xv[rr].y + y1) << 16);
        *(unsigned int*)&sT[(1 + u) * SPAD + cp * 2] = sv;
      }
    }

    // halo fill from neighbors (tagged spin; mutual dep bounds skew to 1 step)
    if (!last) {
      const int o = tid & 127;
      const bool left_side = (tid < 128);
      const int srow = left_side ? 0 : 33;
      const bool interior = left_side ? (q > 0) : (q < NCH - 1);
      float yv = 0.f;
      if (interior) {
        const unsigned int* slot = (left_side ? ex_leftp : ex_rightp) + par * 128 + o;
        unsigned int v = __hip_atomic_load(slot, __ATOMIC_RELAXED, __HIP_MEMORY_SCOPE_AGENT);
        while ((v >> 16) != (unsigned int)(t + 1)) {
          __builtin_amdgcn_s_sleep(1);
          v = __hip_atomic_load(slot, __ATOMIC_RELAXED, __HIP_MEMORY_SCOPE_AGENT);
        }
        yv = bf2f((unsigned short)(v & 0xffff));
      }
      const int ug = left_side ? (u0 - 1) : (u0 + CHUNK);
      unsigned short sv = 0;
      if (ug >= 0 && ug < 160) sv = f2bf(xh + yv);
      sT[srow * SPAD + o] = sv;
    }
    barrier_lds();
  }
}

// ---------------------------------------------------------------------------
__global__ __launch_bounds__(256, 1) void fusion_kernel(
    const unsigned short* __restrict__ featbuf, const unsigned short* __restrict__ fwT,
    const float2* __restrict__ fepi, float* __restrict__ out)
{
  __shared__ unsigned short At[32 * 520];   // [m][k], stride 520 (pad)
  const int bx = blockIdx.x;
  const int b = bx / 800, mb = bx - b * 800;
  const long m0 = (long)mb * 32;            // hw base within batch
  const int tid = threadIdx.x, lane = tid & 63, wv = tid >> 6;
  const int ncol = lane & 15, kq = lane >> 4;

  const unsigned short* fp = featbuf + ((long)b * 25600 + m0) * 512;
#pragma unroll
  for (int rr = 0; rr < 8; rr++) {
    const int e = tid + rr * 256;
    const int m = e >> 6, kp = e & 63;
    *(bf16x8*)&At[m * 520 + kp * 8] = *(const bf16x8*)(fp + (long)m * 512 + kp * 8);
  }
  bf16x8 Bf[2][16];
  float2 fe[2];
#pragma unroll
  for (int j = 0; j < 2; j++) {
    const int o = (wv * 2 + j) * 16 + ncol;
    const unsigned short* wp = fwT + (long)o * 512;
#pragma unroll
    for (int kt = 0; kt < 16; kt++)
      Bf[j][kt] = *(const bf16x8*)(wp + kt * 32 + kq * 8);
    fe[j] = fepi[o];
  }
  __syncthreads();

  f32x4 acc[2][2];
#pragma unroll
  for (int mt = 0; mt < 2; mt++)
#pragma unroll
    for (int j = 0; j < 2; j++)
      acc[mt][j] = (f32x4){0.f, 0.f, 0.f, 0.f};
#pragma unroll
  for (int kt = 0; kt < 16; kt++) {
    const bf16x8 A0 = *(const bf16x8*)&At[ncol * 520 + kt * 32 + kq * 8];
    const bf16x8 A1 = *(const bf16x8*)&At[(16 + ncol) * 520 + kt * 32 + kq * 8];
    acc[0][0] = mfma16(A0, Bf[0][kt], acc[0][0]);
    acc[0][1] = mfma16(A0, Bf[1][kt], acc[0][1]);
    acc[1][0] = mfma16(A1, Bf[0][kt], acc[1][0]);
    acc[1][1] = mfma16(A1, Bf[1][kt], acc[1][1]);
  }
#pragma unroll
  for (int mt = 0; mt < 2; mt++)
#pragma unroll
    for (int j = 0; j < 2; j++) {
      const int o = (wv * 2 + j) * 16 + ncol;
      const long hw = m0 + mt * 16 + kq * 4;
      f32x4 v;
#pragma unroll
      for (int r = 0; r < 4; r++) {
        const float z = acc[mt][j][r] * fe[j].x + fe[j].y;
        v[r] = (z > 0.f) ? z : 0.f;
      }
      *(f32x4*)(out + ((long)(b * 128 + o)) * 25600 + hw) = v;  // NCHW, float4
    }
}

// ---------------------------------------------------------------------------
extern "C" void kernel_launch(void* const* d_in, const int* in_sizes, int n_in,
                              void* d_out, int out_size, void* d_ws, size_t ws_size,
                              hipStream_t stream)
{
  if (ws_size < (size_t)WS_TOTAL) return;  // fail visibly rather than corrupt

  const float* x        = (const float*)d_in[0];
  const float* kernels  = (const float*)d_in[1];
  const float* biases   = (const float*)d_in[2];
  const float* bn_gamma = (const float*)d_in[3];
  const float* bn_beta  = (const float*)d_in[4];
  const float* bn_mean  = (const float*)d_in[5];
  const float* bn_var   = (const float*)d_in[6];
  const float* prelu_a  = (const float*)d_in[7];
  const float* fus_w    = (const float*)d_in[8];
  const float* fus_b    = (const float*)d_in[9];
  const float* fbn_g    = (const float*)d_in[10];
  const float* fbn_b    = (const float*)d_in[11];
  const float* fbn_m    = (const float*)d_in[12];
  const float* fbn_v    = (const float*)d_in[13];

  char* ws = (char*)d_ws;
  float*          xT      = (float*)(ws + WS_XT);
  unsigned short* wprep   = (unsigned short*)(ws + WS_WPREP);
  float2*         epi     = (float2*)(ws + WS_EPI);
  unsigned short* fwT     = (unsigned short*)(ws + WS_FWT);
  float2*         fepi    = (float2*)(ws + WS_FEPI);
  unsigned short* featbuf = (unsigned short*)(ws + WS_FEAT);
  unsigned int*   ex      = (unsigned int*)(ws + WS_EX);
  float*          out     = (float*)d_out;

  prep_kernel<<<1027, 256, 0, stream>>>(kernels, biases, bn_gamma, bn_beta, bn_mean, bn_var,
                                        fus_w, fus_b, fbn_g, fbn_b, fbn_m, fbn_v,
                                        wprep, epi, fwT, fepi);
  transpose_kernel<<<dim3(20, 160, 8), 256, 0, stream>>>(x, xT);
  scan_kernel<<<160, 256, 0, stream>>>(xT, wprep, epi, prelu_a, featbuf, ex);
  fusion_kernel<<<6400, 256, 0, stream>>>(featbuf, fwT, fepi, out);
}

// Round 3
// 681.551 us; speedup vs baseline: 1.0303x; 1.0303x over previous
//
#include <hip/hip_runtime.h>
#include <stdint.h>

// ---------------------------------------------------------------------------
// SpatialConvModule: 4-direction spatial propagation (SCNN-like) + fusion GEMM
//   K2 scan (R3): single-barrier step. Double-buffered sT; s(t+1)=x+y built in
//   registers by the y-owning lane (D-fragment layout) and written straight to
//   the next buffer; feat written per-lane as global_store_short off the
//   critical path. Barriers per step: 3 -> 1.
// ---------------------------------------------------------------------------

typedef __attribute__((ext_vector_type(8))) __bf16 bf16x8;
typedef __attribute__((ext_vector_type(4))) float f32x4;

#define DEV static __device__ __forceinline__

DEV unsigned short f2bf(float f) {
  union { float f; unsigned int u; } v; v.f = f;
  unsigned int u = v.u;
  u += 0x7fffu + ((u >> 16) & 1u);   // round-to-nearest-even
  return (unsigned short)(u >> 16);
}
DEV float bf2f(unsigned short s) {
  union { float f; unsigned int u; } v; v.u = ((unsigned int)s) << 16;
  return v.f;
}
DEV f32x4 mfma16(bf16x8 a, bf16x8 b, f32x4 c) {
  return __builtin_amdgcn_mfma_f32_16x16x32_bf16(a, b, c, 0, 0, 0);
}
// LDS-only barrier: does NOT drain vmcnt (global loads/stores stay in flight).
DEV void barrier_lds() {
  asm volatile("s_waitcnt lgkmcnt(0)\n\ts_barrier" ::: "memory");
}

constexpr int Hc = 160, Wc = 160, Bn = 8, Cc = 128;
constexpr int CHUNK = 32, NCH = 5;   // 5 chunks of 32 along the inner axis
constexpr int SPAD = 136;            // sT row stride in bf16 (272B: 16B-aligned rows)

// workspace layout (bytes)
constexpr long WS_XT    = 0;                         // fp32 [8][160][160][128] = 104857600
constexpr long WS_WPREP = 104857600;                 // bf16 [4][128][384]      = 393216
constexpr long WS_EPI   = 105250816;                 // float2 [512]            = 4096
constexpr long WS_FWT   = 105254912;                 // bf16 [128][512]         = 131072
constexpr long WS_FEPI  = 105385984;                 // float2 [128]            = 1024
constexpr long WS_FEAT  = 105387008;                 // bf16 [8][160][160][512] = 209715200
constexpr long WS_EX    = 315102208;                 // u32 [160][2][2][128]    = 327680
constexpr long WS_TOTAL = 315429888;

// ---------------------------------------------------------------------------
__global__ void prep_kernel(const float* __restrict__ kern, const float* __restrict__ bias,
                            const float* __restrict__ bg, const float* __restrict__ bb,
                            const float* __restrict__ bm, const float* __restrict__ bv,
                            const float* __restrict__ fw, const float* __restrict__ fb2,
                            const float* __restrict__ fg, const float* __restrict__ fbt,
                            const float* __restrict__ fm, const float* __restrict__ fv,
                            unsigned short* __restrict__ wprep, float2* __restrict__ epi,
                            unsigned short* __restrict__ fwT, float2* __restrict__ fepi)
{
  int idx = blockIdx.x * 256 + threadIdx.x;
  if (idx < 196608) {                 // wprep[d][o][t*128+c] = kmid[d][o][c][t]
    int c = idx & 127;
    int t = (idx >> 7) % 3;
    int o = (idx / 384) & 127;
    int d = idx / 49152;
    int kh = (d < 2) ? 1 : t;         // rows use k[:,:,1,:], cols use k[:,:,:,1]
    int kw = (d < 2) ? t : 1;
    wprep[idx] = f2bf(kern[(((d * 128 + o) * 128 + c) * 3 + kh) * 3 + kw]);
  }
  int i2 = idx - 196608;              // fusion weights [o][d*128+c] -> bf16
  if (i2 >= 0 && i2 < 65536) fwT[i2] = f2bf(fw[i2]);
  int i3 = idx - 262144;              // per-(d,o) BN fold: y = conv*scale + shift
  if (i3 >= 0 && i3 < 512) {
    float sc = bg[i3] / sqrtf(bv[i3] + 1e-5f);
    epi[i3] = make_float2(sc, (bias[i3] - bm[i3]) * sc + bb[i3]);
  }
  int i4 = idx - 262656;              // fusion BN fold
  if (i4 >= 0 && i4 < 128) {
    float sc = fg[i4] / sqrtf(fv[i4] + 1e-5f);
    fepi[i4] = make_float2(sc, (fb2[i4] - fm[i4]) * sc + fbt[i4]);
  }
}

// ---------------------------------------------------------------------------
__global__ void transpose_kernel(const float* __restrict__ x, float* __restrict__ xT)
{
  __shared__ float tile[32][33];
  int b = blockIdx.z, h = blockIdx.y;
  int c0 = (blockIdx.x / 5) * 32, w0 = (blockIdx.x % 5) * 32;
  int tx = threadIdx.x & 31, ty = threadIdx.x >> 5;
#pragma unroll
  for (int r = 0; r < 4; r++) {
    int c = c0 + ty + 8 * r;
    tile[ty + 8 * r][tx] = x[(((long)b * 128 + c) * 160 + h) * 160 + w0 + tx];
  }
  __syncthreads();
#pragma unroll
  for (int r = 0; r < 4; r++) {
    int w = w0 + ty + 8 * r;
    xT[(((long)b * 160 + h) * 160 + w) * 128 + c0 + tx] = tile[tx][ty + 8 * r];
  }
}

// ---------------------------------------------------------------------------
// scan: bid = q*32 + (d*8+b); bid%8 invariant over q => group stays on one XCD
__global__ __launch_bounds__(256, 1) void scan_kernel(
    const float* __restrict__ xT, const unsigned short* __restrict__ wprep,
    const float2* __restrict__ epi, const float* __restrict__ prelu_a,
    unsigned short* __restrict__ featbuf, unsigned int* __restrict__ ex)
{
  __shared__ unsigned short sbuf[2][34 * SPAD];  // rows: u-1 .. u+32 (halo top/bottom)

  const int bid = blockIdx.x;
  const int q = bid >> 5;          // chunk 0..4
  const int g = bid & 31;          // d*8 + b
  const int d = g >> 3, b = g & 7;
  const bool row_mode = (d < 2);
  const bool rev = (d & 1);
  const int u0 = q * CHUNK;
  const int tid = threadIdx.x;
  const int lane = tid & 63;
  const int wv = tid >> 6;         // wave 0..3; wave handles n-tiles {2wv, 2wv+1}
  const int ncol = lane & 15;      // A-row / B-col / D-col lane index
  const int kq = lane >> 4;        // k-quad / D-row-quad

  const long si = row_mode ? (long)Wc * Cc : (long)Cc;   // scan-axis stride in xT
  const long su = row_mode ? (long)Cc : (long)Wc * Cc;   // inner-axis stride in xT
  const long fi = row_mode ? (long)Wc * 512 : (long)512; // scan-axis stride in feat
  const long fu = row_mode ? (long)512 : (long)Wc * 512; // inner-axis stride in feat
  const float* xb = xT + (long)b * Hc * Wc * Cc;
  unsigned short* fbp = featbuf + (long)b * Hc * Wc * 512 + d * 128;

  // B fragments: stay in registers for all 160 steps. B[k=t*128+c][n=o].
  bf16x8 Bfrag[2][12];
  float2 ep[2];
#pragma unroll
  for (int j = 0; j < 2; j++) {
    const int o = (wv * 2 + j) * 16 + ncol;
    const unsigned short* wp = wprep + ((long)(d * 128 + o)) * 384;
#pragma unroll
    for (int kt = 0; kt < 12; kt++)
      Bfrag[j][kt] = *(const bf16x8*)(wp + kt * 32 + kq * 8);
    ep[j] = epi[d * 128 + o];
  }
  const float aslope = prelu_a[d];

  unsigned int* ex_self = ex + (long)bid * 512;
  const unsigned int* ex_leftp  = ex + (long)(bid - 32) * 512 + 256; // left nbr, its u=31 side
  const unsigned int* ex_rightp = ex + (long)(bid + 32) * 512;       // right nbr, its u=0 side

  // per-lane D-fragment ownership: 16 (row,col) cells
  // row = mt*16 + kq*4 + r (local u), col = (wv*2+j)*16 + ncol (channel)
  const int colbase0 = (wv * 2) * 16 + ncol;       // j=0
  const int colbase1 = (wv * 2 + 1) * 16 + ncol;   // j=1

  // halo-thread constants
  const int oh = tid & 127;
  const bool left_side = (tid < 128);
  const int srow = left_side ? 0 : 33;
  const bool interior = left_side ? (q > 0) : (q < NCH - 1);
  const int ug = left_side ? (u0 - 1) : (u0 + CHUNK);
  const bool ug_ok = (ug >= 0 && ug < 160);

  // prologue: s(t=0) = x(i0) + 0 into sbuf[0]
  const int i0 = rev ? (Hc - 1) : 0;
  for (int e = tid; e < 34 * 64; e += 256) {
    const int u = e >> 6, cp = e & 63;
    const int uu = u0 + u - 1;
    unsigned int sv = 0;
    if (uu >= 0 && uu < 160) {
      const float2 xv2 = *(const float2*)(xb + (long)i0 * si + (long)uu * su + cp * 2);
      sv = (unsigned int)f2bf(xv2.x) | ((unsigned int)f2bf(xv2.y) << 16);
    }
    *(unsigned int*)&sbuf[0][u * SPAD + cp * 2] = sv;
  }
  barrier_lds();

#pragma unroll 1
  for (int t = 0; t < 160; t++) {
    const int i = rev ? (159 - t) : t;
    const int inext = rev ? (i - 1) : (i + 1);
    const bool last = (t == 159);
    const int par = t & 1;
    unsigned short* cur = sbuf[t & 1];
    unsigned short* nxt = sbuf[(t & 1) ^ 1];

    // prefetch next scan-line x per-lane in D layout (consumed in s-build;
    // ~700 cyc of MFMA+epilogue slack hides the (mostly-L3) latency)
    float xn[2][2][4];
    float xh = 0.f;
    if (!last) {
      const float* xrow = xb + (long)inext * si;
#pragma unroll
      for (int mt = 0; mt < 2; mt++)
#pragma unroll
        for (int j = 0; j < 2; j++) {
          const int col = j ? colbase1 : colbase0;
#pragma unroll
          for (int r = 0; r < 4; r++) {
            const int row = mt * 16 + kq * 4 + r;
            xn[mt][j][r] = xrow[(long)(u0 + row) * su + col];
          }
        }
      if (ug_ok) xh = xrow[(long)ug * su + oh];
    }

    // MFMA: D[m=u][n=o] = sum_k s[m+t-1][c] * w[o][t*128+c]
    f32x4 acc[2][2];
#pragma unroll
    for (int mt = 0; mt < 2; mt++)
#pragma unroll
      for (int j = 0; j < 2; j++)
        acc[mt][j] = (f32x4){0.f, 0.f, 0.f, 0.f};
#pragma unroll
    for (int kt = 0; kt < 12; kt++) {
      const int tt = kt >> 2;                         // tap 0..2
      const int c0 = ((kt & 3) << 5) + (kq << 3);     // c within tap
      const bf16x8 A0 = *(const bf16x8*)&cur[(ncol + tt) * SPAD + c0];
      const bf16x8 A1 = *(const bf16x8*)&cur[(16 + ncol + tt) * SPAD + c0];
      acc[0][0] = mfma16(A0, Bfrag[0][kt], acc[0][0]);
      acc[0][1] = mfma16(A0, Bfrag[1][kt], acc[0][1]);
      acc[1][0] = mfma16(A1, Bfrag[0][kt], acc[1][0]);
      acc[1][1] = mfma16(A1, Bfrag[1][kt], acc[1][1]);
    }

    // epilogue: BN fold + PReLU; keep float (for s) and bf16 (for feat/publish)
    float yf[2][2][4];
    unsigned short yb[2][2][4];
#pragma unroll
    for (int mt = 0; mt < 2; mt++)
#pragma unroll
      for (int j = 0; j < 2; j++)
#pragma unroll
        for (int r = 0; r < 4; r++) {
          float v = acc[mt][j][r] * ep[j].x + ep[j].y;
          v = (v >= 0.f) ? v : (aslope * v);
          yf[mt][j][r] = v;
          yb[mt][j][r] = f2bf(v);
        }

    // publish boundary rows ASAP: one word = (t+1)<<16 | bf16(y)
    {
      const unsigned int tagv = ((unsigned int)(t + 1)) << 16;
      if (kq == 0) {                          // row 0 (u_local=0): mt=0,r=0
        __hip_atomic_store(&ex_self[par * 128 + colbase0], tagv | (unsigned int)yb[0][0][0],
                           __ATOMIC_RELAXED, __HIP_MEMORY_SCOPE_AGENT);
        __hip_atomic_store(&ex_self[par * 128 + colbase1], tagv | (unsigned int)yb[0][1][0],
                           __ATOMIC_RELAXED, __HIP_MEMORY_SCOPE_AGENT);
      }
      if (kq == 3) {                          // row 31 (u_local=31): mt=1,r=3
        __hip_atomic_store(&ex_self[256 + par * 128 + colbase0], tagv | (unsigned int)yb[1][0][3],
                           __ATOMIC_RELAXED, __HIP_MEMORY_SCOPE_AGENT);
        __hip_atomic_store(&ex_self[256 + par * 128 + colbase1], tagv | (unsigned int)yb[1][1][3],
                           __ATOMIC_RELAXED, __HIP_MEMORY_SCOPE_AGENT);
      }
    }

    // feat store (off critical path) + s-build straight into nxt buffer
    unsigned short* frow = fbp + (long)i * fi;
#pragma unroll
    for (int mt = 0; mt < 2; mt++)
#pragma unroll
      for (int j = 0; j < 2; j++) {
        const int col = j ? colbase1 : colbase0;
#pragma unroll
        for (int r = 0; r < 4; r++) {
          const int row = mt * 16 + kq * 4 + r;
          frow[(long)(u0 + row) * fu + col] = yb[mt][j][r];
          if (!last)
            nxt[(1 + row) * SPAD + col] = f2bf(xn[mt][j][r] + yf[mt][j][r]);
        }
      }

    // halo fill from neighbors (tagged spin; two-sided coupling bounds skew to 1)
    if (!last) {
      float yv = 0.f;
      if (interior) {
        const unsigned int* slot = (left_side ? ex_leftp : ex_rightp) + par * 128 + oh;
        unsigned int v = __hip_atomic_load(slot, __ATOMIC_RELAXED, __HIP_MEMORY_SCOPE_AGENT);
        while ((v >> 16) != (unsigned int)(t + 1)) {
          __builtin_amdgcn_s_sleep(1);
          v = __hip_atomic_load(slot, __ATOMIC_RELAXED, __HIP_MEMORY_SCOPE_AGENT);
        }
        yv = bf2f((unsigned short)(v & 0xffff));
      }
      unsigned short sv = 0;
      if (ug_ok) sv = f2bf(xh + yv);
      nxt[srow * SPAD + oh] = sv;
    }
    barrier_lds();   // s(t+1) complete; vmem (feat stores, prefetches) stays in flight
  }
}

// ---------------------------------------------------------------------------
__global__ __launch_bounds__(256, 1) void fusion_kernel(
    const unsigned short* __restrict__ featbuf, const unsigned short* __restrict__ fwT,
    const float2* __restrict__ fepi, float* __restrict__ out)
{
  __shared__ unsigned short At[32 * 520];   // [m][k], stride 520 (pad)
  const int bx = blockIdx.x;
  const int b = bx / 800, mb = bx - b * 800;
  const long m0 = (long)mb * 32;            // hw base within batch
  const int tid = threadIdx.x, lane = tid & 63, wv = tid >> 6;
  const int ncol = lane & 15, kq = lane >> 4;

  const unsigned short* fp = featbuf + ((long)b * 25600 + m0) * 512;
#pragma unroll
  for (int rr = 0; rr < 8; rr++) {
    const int e = tid + rr * 256;
    const int m = e >> 6, kp = e & 63;
    *(bf16x8*)&At[m * 520 + kp * 8] = *(const bf16x8*)(fp + (long)m * 512 + kp * 8);
  }
  bf16x8 Bf[2][16];
  float2 fe[2];
#pragma unroll
  for (int j = 0; j < 2; j++) {
    const int o = (wv * 2 + j) * 16 + ncol;
    const unsigned short* wp = fwT + (long)o * 512;
#pragma unroll
    for (int kt = 0; kt < 16; kt++)
      Bf[j][kt] = *(const bf16x8*)(wp + kt * 32 + kq * 8);
    fe[j] = fepi[o];
  }
  __syncthreads();

  f32x4 acc[2][2];
#pragma unroll
  for (int mt = 0; mt < 2; mt++)
#pragma unroll
    for (int j = 0; j < 2; j++)
      acc[mt][j] = (f32x4){0.f, 0.f, 0.f, 0.f};
#pragma unroll
  for (int kt = 0; kt < 16; kt++) {
    const bf16x8 A0 = *(const bf16x8*)&At[ncol * 520 + kt * 32 + kq * 8];
    const bf16x8 A1 = *(const bf16x8*)&At[(16 + ncol) * 520 + kt * 32 + kq * 8];
    acc[0][0] = mfma16(A0, Bf[0][kt], acc[0][0]);
    acc[0][1] = mfma16(A0, Bf[1][kt], acc[0][1]);
    acc[1][0] = mfma16(A1, Bf[0][kt], acc[1][0]);
    acc[1][1] = mfma16(A1, Bf[1][kt], acc[1][1]);
  }
#pragma unroll
  for (int mt = 0; mt < 2; mt++)
#pragma unroll
    for (int j = 0; j < 2; j++) {
      const int o = (wv * 2 + j) * 16 + ncol;
      const long hw = m0 + mt * 16 + kq * 4;
      f32x4 v;
#pragma unroll
      for (int r = 0; r < 4; r++) {
        const float z = acc[mt][j][r] * fe[j].x + fe[j].y;
        v[r] = (z > 0.f) ? z : 0.f;
      }
      *(f32x4*)(out + ((long)(b * 128 + o)) * 25600 + hw) = v;  // NCHW, float4
    }
}

// ---------------------------------------------------------------------------
extern "C" void kernel_launch(void* const* d_in, const int* in_sizes, int n_in,
                              void* d_out, int out_size, void* d_ws, size_t ws_size,
                              hipStream_t stream)
{
  if (ws_size < (size_t)WS_TOTAL) return;  // fail visibly rather than corrupt

  const float* x        = (const float*)d_in[0];
  const float* kernels  = (const float*)d_in[1];
  const float* biases   = (const float*)d_in[2];
  const float* bn_gamma = (const float*)d_in[3];
  const float* bn_beta  = (const float*)d_in[4];
  const float* bn_mean  = (const float*)d_in[5];
  const float* bn_var   = (const float*)d_in[6];
  const float* prelu_a  = (const float*)d_in[7];
  const float* fus_w    = (const float*)d_in[8];
  const float* fus_b    = (const float*)d_in[9];
  const float* fbn_g    = (const float*)d_in[10];
  const float* fbn_b    = (const float*)d_in[11];
  const float* fbn_m    = (const float*)d_in[12];
  const float* fbn_v    = (const float*)d_in[13];

  char* ws = (char*)d_ws;
  float*          xT      = (float*)(ws + WS_XT);
  unsigned short* wprep   = (unsigned short*)(ws + WS_WPREP);
  float2*         epi     = (float2*)(ws + WS_EPI);
  unsigned short* fwT     = (unsigned short*)(ws + WS_FWT);
  float2*         fepi    = (float2*)(ws + WS_FEPI);
  unsigned short* featbuf = (unsigned short*)(ws + WS_FEAT);
  unsigned int*   ex      = (unsigned int*)(ws + WS_EX);
  float*          out     = (float*)d_out;

  prep_kernel<<<1027, 256, 0, stream>>>(kernels, biases, bn_gamma, bn_beta, bn_mean, bn_var,
                                        fus_w, fus_b, fbn_g, fbn_b, fbn_m, fbn_v,
                                        wprep, epi, fwT, fepi);
  transpose_kernel<<<dim3(20, 160, 8), 256, 0, stream>>>(x, xT);
  scan_kernel<<<160, 256, 0, stream>>>(xT, wprep, epi, prelu_a, featbuf, ex);
  fusion_kernel<<<6400, 256, 0, stream>>>(featbuf, fwT, fepi, out);
}

// Round 4
// 609.293 us; speedup vs baseline: 1.1525x; 1.1186x over previous
//
#include <hip/hip_runtime.h>
#include <stdint.h>

// ---------------------------------------------------------------------------
// SpatialConvModule: 4-direction spatial propagation (SCNN-like) + fusion GEMM
//   K2 scan (R4): TLP fix. 160 blocks x 512 threads (8 waves = 2 waves/SIMD).
//   Each block runs TWO independent direction-streams (fwd/bwd of one mode)
//   on M=16 chunks (10 chunks/axis). Streams interleave on the SIMDs so one
//   stream's VALU hides the other's LDS/L2 latency. Cell offsets are
//   loop-invariant; per-step addressing is one uniform base bump.
// ---------------------------------------------------------------------------

typedef __attribute__((ext_vector_type(8))) __bf16 bf16x8;
typedef __attribute__((ext_vector_type(4))) float f32x4;

#define DEV static __device__ __forceinline__

DEV unsigned short f2bf(float f) {
  union { float f; unsigned int u; } v; v.f = f;
  unsigned int u = v.u;
  u += 0x7fffu + ((u >> 16) & 1u);   // round-to-nearest-even
  return (unsigned short)(u >> 16);
}
DEV float bf2f(unsigned short s) {
  union { float f; unsigned int u; } v; v.u = ((unsigned int)s) << 16;
  return v.f;
}
DEV f32x4 mfma16(bf16x8 a, bf16x8 b, f32x4 c) {
  return __builtin_amdgcn_mfma_f32_16x16x32_bf16(a, b, c, 0, 0, 0);
}
// LDS-only barrier: does NOT drain vmcnt (global loads/stores stay in flight).
DEV void barrier_lds() {
  asm volatile("s_waitcnt lgkmcnt(0)\n\ts_barrier" ::: "memory");
}

constexpr int Hc = 160, Wc = 160, Cc = 128;
constexpr int CHUNK = 16, NCH = 10;  // 10 chunks of 16 along the inner axis
constexpr int ROWS = 18;             // u0-1 .. u0+16 (halo top/bottom)
constexpr int SPAD = 136;            // sT row stride in bf16

// workspace layout (bytes)
constexpr long WS_XT    = 0;                         // fp32 [8][160][160][128] = 104857600
constexpr long WS_WPREP = 104857600;                 // bf16 [4][128][384]      = 393216
constexpr long WS_EPI   = 105250816;                 // float2 [512]            = 4096
constexpr long WS_FWT   = 105254912;                 // bf16 [128][512]         = 131072
constexpr long WS_FEPI  = 105385984;                 // float2 [128]            = 1024
constexpr long WS_FEAT  = 105387008;                 // bf16 [8][160][160][512] = 209715200
constexpr long WS_EX    = 315102208;                 // u32 [320][2][2][128]    = 655360
constexpr long WS_TOTAL = 315757568;

// ---------------------------------------------------------------------------
__global__ void prep_kernel(const float* __restrict__ kern, const float* __restrict__ bias,
                            const float* __restrict__ bg, const float* __restrict__ bb,
                            const float* __restrict__ bm, const float* __restrict__ bv,
                            const float* __restrict__ fw, const float* __restrict__ fb2,
                            const float* __restrict__ fg, const float* __restrict__ fbt,
                            const float* __restrict__ fm, const float* __restrict__ fv,
                            unsigned short* __restrict__ wprep, float2* __restrict__ epi,
                            unsigned short* __restrict__ fwT, float2* __restrict__ fepi)
{
  int idx = blockIdx.x * 256 + threadIdx.x;
  if (idx < 196608) {                 // wprep[d][o][t*128+c] = kmid[d][o][c][t]
    int c = idx & 127;
    int t = (idx >> 7) % 3;
    int o = (idx / 384) & 127;
    int d = idx / 49152;
    int kh = (d < 2) ? 1 : t;         // rows use k[:,:,1,:], cols use k[:,:,:,1]
    int kw = (d < 2) ? t : 1;
    wprep[idx] = f2bf(kern[(((d * 128 + o) * 128 + c) * 3 + kh) * 3 + kw]);
  }
  int i2 = idx - 196608;              // fusion weights [o][d*128+c] -> bf16
  if (i2 >= 0 && i2 < 65536) fwT[i2] = f2bf(fw[i2]);
  int i3 = idx - 262144;              // per-(d,o) BN fold: y = conv*scale + shift
  if (i3 >= 0 && i3 < 512) {
    float sc = bg[i3] / sqrtf(bv[i3] + 1e-5f);
    epi[i3] = make_float2(sc, (bias[i3] - bm[i3]) * sc + bb[i3]);
  }
  int i4 = idx - 262656;              // fusion BN fold
  if (i4 >= 0 && i4 < 128) {
    float sc = fg[i4] / sqrtf(fv[i4] + 1e-5f);
    fepi[i4] = make_float2(sc, (fb2[i4] - fm[i4]) * sc + fbt[i4]);
  }
}

// ---------------------------------------------------------------------------
__global__ void transpose_kernel(const float* __restrict__ x, float* __restrict__ xT)
{
  __shared__ float tile[32][33];
  int b = blockIdx.z, h = blockIdx.y;
  int c0 = (blockIdx.x / 5) * 32, w0 = (blockIdx.x % 5) * 32;
  int tx = threadIdx.x & 31, ty = threadIdx.x >> 5;
#pragma unroll
  for (int r = 0; r < 4; r++) {
    int c = c0 + ty + 8 * r;
    tile[ty + 8 * r][tx] = x[(((long)b * 128 + c) * 160 + h) * 160 + w0 + tx];
  }
  __syncthreads();
#pragma unroll
  for (int r = 0; r < 4; r++) {
    int w = w0 + ty + 8 * r;
    xT[(((long)b * 160 + h) * 160 + w) * 128 + c0 + tx] = tile[tx][ty + 8 * r];
  }
}

// ---------------------------------------------------------------------------
// scan: bid = q*16 + (p*8+b); bid%8 invariant over q => chain stays on one XCD.
// 512 threads: waves 0-3 = stream 0 (d=2p), waves 4-7 = stream 1 (d=2p+1).
__global__ __launch_bounds__(512, 2) void scan_kernel(
    const float* __restrict__ xT, const unsigned short* __restrict__ wprep,
    const float2* __restrict__ epi, const float* __restrict__ prelu_a,
    unsigned short* __restrict__ featbuf, unsigned int* __restrict__ ex)
{
  __shared__ unsigned short sbuf[2][2][ROWS * SPAD];  // [stream][parity][rows]

  const int bid = blockIdx.x;
  const int q = bid >> 4;            // chunk 0..9
  const int g = bid & 15;            // p*8 + b
  const int p = g >> 3, b = g & 7;   // p: 0=row-mode(d0,d1), 1=col-mode(d2,d3)
  const int tid = threadIdx.x;
  const int wv = tid >> 6;           // wave 0..7
  const int s = wv >> 2;             // stream 0/1 within block
  const int wl = wv & 3;             // wave-in-stream: n-tiles {2wl, 2wl+1}
  const int lane = tid & 63;
  const int ncol = lane & 15;        // A-row / B-col / D-col lane index
  const int kq = lane >> 4;          // k-quad / D-row-quad
  const int d = p * 2 + s;
  const bool rev = (s != 0);
  const int u0 = q * CHUNK;

  const bool row_mode = (p == 0);
  const long si = row_mode ? (long)Wc * Cc : (long)Cc;   // scan-axis stride in xT
  const int  su = row_mode ? Cc : Wc * Cc;               // inner-axis stride in xT
  const long fi = row_mode ? (long)Wc * 512 : (long)512; // scan-axis stride in feat
  const int  fu = row_mode ? 512 : Wc * 512;             // inner-axis stride in feat
  const float* xb = xT + (long)b * Hc * Wc * Cc;
  unsigned short* fbp = featbuf + (long)b * Hc * Wc * 512 + d * 128;

  // B fragments: registers for all 160 steps. B[k=t*128+c][n=o].
  bf16x8 Bfrag[2][12];
  float2 ep[2];
  int colj[2];
#pragma unroll
  for (int j = 0; j < 2; j++) {
    const int o = (wl * 2 + j) * 16 + ncol;
    colj[j] = o;
    const unsigned short* wp = wprep + ((long)(d * 128 + o)) * 384;
#pragma unroll
    for (int kt = 0; kt < 12; kt++)
      Bfrag[j][kt] = *(const bf16x8*)(wp + kt * 32 + kq * 8);
    ep[j] = epi[d * 128 + o];
  }
  const float aslope = prelu_a[d];

  // loop-invariant per-cell offsets (element units, fit in 32-bit)
  int xoff[2][4], foff[2][4];
#pragma unroll
  for (int j = 0; j < 2; j++)
#pragma unroll
    for (int r = 0; r < 4; r++) {
      const int row = kq * 4 + r;
      xoff[j][r] = (u0 + row) * su + colj[j];
      foff[j][r] = (u0 + row) * fu + colj[j];
    }

  // exchange: sid = d*80 + b*10 + q; layout [sid][side][par][128]
  const int sid = d * 80 + b * 10 + q;
  unsigned int* ex_self = ex + (long)sid * 512;

  // halo thread mapping: each of the 512 threads owns one (stream, side, ch)
  const int hside = (tid >> 7) & 1;          // 0 = low (u0-1), 1 = high (u0+16)
  const int oh = tid & 127;
  const bool interior = hside ? (q < NCH - 1) : (q > 0);
  const int ug = hside ? (u0 + CHUNK) : (u0 - 1);
  const bool ug_ok = (ug >= 0 && ug < 160);
  const int srow = hside ? (ROWS - 1) : 0;
  const int xhoff = ug_ok ? (ug * su + oh) : 0;
  const unsigned int* ex_nbr = hside ? (ex + (long)(sid + 1) * 512)
                                     : (ex + (long)(sid - 1) * 512 + 256);

  // prologue: s(t=0) = x(i0) into sbuf[s][0]
  const int i0 = rev ? (Hc - 1) : 0;
  const int tids = tid & 255;
  for (int e = tids; e < ROWS * 64; e += 256) {
    const int u = e >> 6, cp = e & 63;
    const int uu = u0 + u - 1;
    unsigned int sv = 0;
    if (uu >= 0 && uu < 160) {
      const float2 xv2 = *(const float2*)(xb + (long)i0 * si + (long)uu * su + cp * 2);
      sv = (unsigned int)f2bf(xv2.x) | ((unsigned int)f2bf(xv2.y) << 16);
    }
    *(unsigned int*)&sbuf[s][0][u * SPAD + cp * 2] = sv;
  }
  barrier_lds();

#pragma unroll 1
  for (int t = 0; t < 160; t++) {
    const int i = rev ? (159 - t) : t;
    const int inext = rev ? (i - 1) : (i + 1);
    const bool last = (t == 159);
    const int par = t & 1;
    const unsigned short* cur = sbuf[s][par];
    unsigned short* nxt = sbuf[s][par ^ 1];

    // prefetch next scan-line x (per-lane, loop-invariant offsets off a
    // per-step uniform base; latency hidden under MFMA+epilogue)
    const float* xrow = xb + (long)inext * si;
    float xn[2][4];
    float xh = 0.f;
    if (!last) {
#pragma unroll
      for (int j = 0; j < 2; j++)
#pragma unroll
        for (int r = 0; r < 4; r++)
          xn[j][r] = xrow[xoff[j][r]];
      if (ug_ok) xh = xrow[xhoff];
    }

    // MFMA: D[m][n=o] = sum_k s[m-1+t][c] * w[o][t*128+c]  (M=16 tile)
    f32x4 acc[2];
    acc[0] = (f32x4){0.f, 0.f, 0.f, 0.f};
    acc[1] = (f32x4){0.f, 0.f, 0.f, 0.f};
#pragma unroll
    for (int kt = 0; kt < 12; kt++) {
      const int tt = kt >> 2;                         // tap 0..2
      const int c0 = ((kt & 3) << 5) + (kq << 3);     // c within tap
      const bf16x8 A0 = *(const bf16x8*)&cur[(ncol + tt) * SPAD + c0];
      acc[0] = mfma16(A0, Bfrag[0][kt], acc[0]);
      acc[1] = mfma16(A0, Bfrag[1][kt], acc[1]);
    }

    // epilogue: BN fold + PReLU
    float yf[2][4];
    unsigned short yb[2][4];
#pragma unroll
    for (int j = 0; j < 2; j++)
#pragma unroll
      for (int r = 0; r < 4; r++) {
        float v = acc[j][r] * ep[j].x + ep[j].y;
        v = (v >= 0.f) ? v : (aslope * v);
        yf[j][r] = v;
        yb[j][r] = f2bf(v);
      }

    // publish boundary rows: word = (t+1)<<16 | bf16(y)
    {
      const unsigned int tagv = ((unsigned int)(t + 1)) << 16;
      if (kq == 0) {                          // local row 0
        __hip_atomic_store(&ex_self[par * 128 + colj[0]], tagv | (unsigned int)yb[0][0],
                           __ATOMIC_RELAXED, __HIP_MEMORY_SCOPE_AGENT);
        __hip_atomic_store(&ex_self[par * 128 + colj[1]], tagv | (unsigned int)yb[1][0],
                           __ATOMIC_RELAXED, __HIP_MEMORY_SCOPE_AGENT);
      }
      if (kq == 3) {                          // local row 15
        __hip_atomic_store(&ex_self[256 + par * 128 + colj[0]], tagv | (unsigned int)yb[0][3],
                           __ATOMIC_RELAXED, __HIP_MEMORY_SCOPE_AGENT);
        __hip_atomic_store(&ex_self[256 + par * 128 + colj[1]], tagv | (unsigned int)yb[1][3],
                           __ATOMIC_RELAXED, __HIP_MEMORY_SCOPE_AGENT);
      }
    }

    // feat store (off critical path) + s-build straight into nxt buffer
    unsigned short* frow = fbp + (long)i * fi;
#pragma unroll
    for (int j = 0; j < 2; j++)
#pragma unroll
      for (int r = 0; r < 4; r++) {
        frow[foff[j][r]] = yb[j][r];
        if (!last)
          nxt[(1 + kq * 4 + r) * SPAD + colj[j]] = f2bf(xn[j][r] + yf[j][r]);
      }

    // halo fill from neighbors (tagged spin; mutual coupling bounds skew to 1)
    if (!last) {
      float yv = 0.f;
      if (interior) {
        const unsigned int* slot = ex_nbr + par * 128 + oh;
        unsigned int v = __hip_atomic_load(slot, __ATOMIC_RELAXED, __HIP_MEMORY_SCOPE_AGENT);
        while ((v >> 16) != (unsigned int)(t + 1)) {
          __builtin_amdgcn_s_sleep(1);
          v = __hip_atomic_load(slot, __ATOMIC_RELAXED, __HIP_MEMORY_SCOPE_AGENT);
        }
        yv = bf2f((unsigned short)(v & 0xffff));
      }
      unsigned short sv = 0;
      if (ug_ok) sv = f2bf(xh + yv);
      nxt[srow * SPAD + oh] = sv;
    }
    barrier_lds();   // s(t+1) complete; vmem (feat stores, prefetches) in flight
  }
}

// ---------------------------------------------------------------------------
__global__ __launch_bounds__(256, 1) void fusion_kernel(
    const unsigned short* __restrict__ featbuf, const unsigned short* __restrict__ fwT,
    const float2* __restrict__ fepi, float* __restrict__ out)
{
  __shared__ unsigned short At[32 * 520];   // [m][k], stride 520 (pad)
  const int bx = blockIdx.x;
  const int b = bx / 800, mb = bx - b * 800;
  const long m0 = (long)mb * 32;            // hw base within batch
  const int tid = threadIdx.x, lane = tid & 63, wv = tid >> 6;
  const int ncol = lane & 15, kq = lane >> 4;

  const unsigned short* fp = featbuf + ((long)b * 25600 + m0) * 512;
#pragma unroll
  for (int rr = 0; rr < 8; rr++) {
    const int e = tid + rr * 256;
    const int m = e >> 6, kp = e & 63;
    *(bf16x8*)&At[m * 520 + kp * 8] = *(const bf16x8*)(fp + (long)m * 512 + kp * 8);
  }
  bf16x8 Bf[2][16];
  float2 fe[2];
#pragma unroll
  for (int j = 0; j < 2; j++) {
    const int o = (wv * 2 + j) * 16 + ncol;
    const unsigned short* wp = fwT + (long)o * 512;
#pragma unroll
    for (int kt = 0; kt < 16; kt++)
      Bf[j][kt] = *(const bf16x8*)(wp + kt * 32 + kq * 8);
    fe[j] = fepi[o];
  }
  __syncthreads();

  f32x4 acc[2][2];
#pragma unroll
  for (int mt = 0; mt < 2; mt++)
#pragma unroll
    for (int j = 0; j < 2; j++)
      acc[mt][j] = (f32x4){0.f, 0.f, 0.f, 0.f};
#pragma unroll
  for (int kt = 0; kt < 16; kt++) {
    const bf16x8 A0 = *(const bf16x8*)&At[ncol * 520 + kt * 32 + kq * 8];
    const bf16x8 A1 = *(const bf16x8*)&At[(16 + ncol) * 520 + kt * 32 + kq * 8];
    acc[0][0] = mfma16(A0, Bf[0][kt], acc[0][0]);
    acc[0][1] = mfma16(A0, Bf[1][kt], acc[0][1]);
    acc[1][0] = mfma16(A1, Bf[0][kt], acc[1][0]);
    acc[1][1] = mfma16(A1, Bf[1][kt], acc[1][1]);
  }
#pragma unroll
  for (int mt = 0; mt < 2; mt++)
#pragma unroll
    for (int j = 0; j < 2; j++) {
      const int o = (wv * 2 + j) * 16 + ncol;
      const long hw = m0 + mt * 16 + kq * 4;
      f32x4 v;
#pragma unroll
      for (int r = 0; r < 4; r++) {
        const float z = acc[mt][j][r] * fe[j].x + fe[j].y;
        v[r] = (z > 0.f) ? z : 0.f;
      }
      *(f32x4*)(out + ((long)(b * 128 + o)) * 25600 + hw) = v;  // NCHW, float4
    }
}

// ---------------------------------------------------------------------------
extern "C" void kernel_launch(void* const* d_in, const int* in_sizes, int n_in,
                              void* d_out, int out_size, void* d_ws, size_t ws_size,
                              hipStream_t stream)
{
  if (ws_size < (size_t)WS_TOTAL) return;  // fail visibly rather than corrupt

  const float* x        = (const float*)d_in[0];
  const float* kernels  = (const float*)d_in[1];
  const float* biases   = (const float*)d_in[2];
  const float* bn_gamma = (const float*)d_in[3];
  const float* bn_beta  = (const float*)d_in[4];
  const float* bn_mean  = (const float*)d_in[5];
  const float* bn_var   = (const float*)d_in[6];
  const float* prelu_a  = (const float*)d_in[7];
  const float* fus_w    = (const float*)d_in[8];
  const float* fus_b    = (const float*)d_in[9];
  const float* fbn_g    = (const float*)d_in[10];
  const float* fbn_b    = (const float*)d_in[11];
  const float* fbn_m    = (const float*)d_in[12];
  const float* fbn_v    = (const float*)d_in[13];

  char* ws = (char*)d_ws;
  float*          xT      = (float*)(ws + WS_XT);
  unsigned short* wprep   = (unsigned short*)(ws + WS_WPREP);
  float2*         epi     = (float2*)(ws + WS_EPI);
  unsigned short* fwT     = (unsigned short*)(ws + WS_FWT);
  float2*         fepi    = (float2*)(ws + WS_FEPI);
  unsigned short* featbuf = (unsigned short*)(ws + WS_FEAT);
  unsigned int*   ex      = (unsigned int*)(ws + WS_EX);
  float*          out     = (float*)d_out;

  prep_kernel<<<1027, 256, 0, stream>>>(kernels, biases, bn_gamma, bn_beta, bn_mean, bn_var,
                                        fus_w, fus_b, fbn_g, fbn_b, fbn_m, fbn_v,
                                        wprep, epi, fwT, fepi);
  transpose_kernel<<<dim3(20, 160, 8), 256, 0, stream>>>(x, xT);
  scan_kernel<<<160, 512, 0, stream>>>(xT, wprep, epi, prelu_a, featbuf, ex);
  fusion_kernel<<<6400, 256, 0, stream>>>(featbuf, fwT, fepi, out);
}